// Round 2
// baseline (30.141 us; speedup 1.0000x reference)
//
#include <hip/hip_runtime.h>
#include <math.h>

#define B_    256
#define K_    5
#define N_    4096
#define NPAIR (B_ * K_)     // 1280
#define NMOM  17

// ---------------------------------------------------------------------------
// Kernel 1: per-(b,k) moment reduction over N=4096 points.
// Outputs 17 floats per pair: sumP[3], sumQ[3], sum|p|^2, sum|q|^2, H_raw[9]
// ---------------------------------------------------------------------------
__global__ __launch_bounds__(256) void kabsch_moments(
    const float* __restrict__ preds, const float* __restrict__ target,
    float* __restrict__ mout) {
  const int pair = blockIdx.x;        // 0..1279
  const int b = pair / K_;
  const int tid = threadIdx.x;

  const float4* __restrict__ P4 =
      reinterpret_cast<const float4*>(preds) + (size_t)pair * (N_ * 3 / 4);
  const float4* __restrict__ Q4 =
      reinterpret_cast<const float4*>(target) + (size_t)b * (N_ * 3 / 4);

  float acc[NMOM];
#pragma unroll
  for (int i = 0; i < NMOM; ++i) acc[i] = 0.f;

  // 4096 points = 1024 chunks of 4 points (3 float4 each); 256 threads x 4 chunks
#pragma unroll
  for (int j = 0; j < 4; ++j) {
    const int c = tid + j * 256;
    const float4 a0 = P4[3 * c + 0], a1 = P4[3 * c + 1], a2 = P4[3 * c + 2];
    const float4 b0 = Q4[3 * c + 0], b1 = Q4[3 * c + 1], b2 = Q4[3 * c + 2];
    const float p[4][3] = {{a0.x, a0.y, a0.z},
                           {a0.w, a1.x, a1.y},
                           {a1.z, a1.w, a2.x},
                           {a2.y, a2.z, a2.w}};
    const float q[4][3] = {{b0.x, b0.y, b0.z},
                           {b0.w, b1.x, b1.y},
                           {b1.z, b1.w, b2.x},
                           {b2.y, b2.z, b2.w}};
#pragma unroll
    for (int m = 0; m < 4; ++m) {
      const float px = p[m][0], py = p[m][1], pz = p[m][2];
      const float qx = q[m][0], qy = q[m][1], qz = q[m][2];
      acc[0] += px; acc[1] += py; acc[2] += pz;
      acc[3] += qx; acc[4] += qy; acc[5] += qz;
      acc[6] = fmaf(px, px, fmaf(py, py, fmaf(pz, pz, acc[6])));
      acc[7] = fmaf(qx, qx, fmaf(qy, qy, fmaf(qz, qz, acc[7])));
      acc[8]  = fmaf(px, qx, acc[8]);
      acc[9]  = fmaf(px, qy, acc[9]);
      acc[10] = fmaf(px, qz, acc[10]);
      acc[11] = fmaf(py, qx, acc[11]);
      acc[12] = fmaf(py, qy, acc[12]);
      acc[13] = fmaf(py, qz, acc[13]);
      acc[14] = fmaf(pz, qx, acc[14]);
      acc[15] = fmaf(pz, qy, acc[15]);
      acc[16] = fmaf(pz, qz, acc[16]);
    }
  }

  // wave64 butterfly reduce, then cross-wave via LDS
#pragma unroll
  for (int off = 32; off > 0; off >>= 1) {
#pragma unroll
    for (int i = 0; i < NMOM; ++i) acc[i] += __shfl_down(acc[i], off, 64);
  }

  __shared__ float red[4][NMOM];
  const int lane = tid & 63, wid = tid >> 6;
  if (lane == 0) {
#pragma unroll
    for (int i = 0; i < NMOM; ++i) red[wid][i] = acc[i];
  }
  __syncthreads();
  if (tid < NMOM) {
    mout[(size_t)pair * NMOM + tid] =
        red[0][tid] + red[1][tid] + red[2][tid] + red[3][tid];
  }
}

// ---------------------------------------------------------------------------
// Kernel 2: per-pair 3x3 "SVD" (eigendecomposition of H^T H) + rmsd.
// Reproduces the reference's buggy R = Vh diag(1,1,d) U^T via
//   tr(H R) = S0*M00 + S1*M11 + d*S2*M22,  M = Vh*Vh, d = sign(det H).
// ---------------------------------------------------------------------------
__device__ inline void cross3(const double* a, const double* b, double* c) {
  c[0] = a[1] * b[2] - a[2] * b[1];
  c[1] = a[2] * b[0] - a[0] * b[2];
  c[2] = a[0] * b[1] - a[1] * b[0];
}
__device__ inline double dot3(const double* a, const double* b) {
  return a[0] * b[0] + a[1] * b[1] + a[2] * b[2];
}
__device__ inline void fixsign3(double* v) {
  const double a0 = fabs(v[0]), a1 = fabs(v[1]), a2 = fabs(v[2]);
  const int i = (a0 >= a1 && a0 >= a2) ? 0 : ((a1 >= a2) ? 1 : 2);
  if (v[i] < 0.0) { v[0] = -v[0]; v[1] = -v[1]; v[2] = -v[2]; }
}
__device__ inline void eigvec3(const double A[3][3], double lam, double* v) {
  const double r0[3] = {A[0][0] - lam, A[0][1], A[0][2]};
  const double r1[3] = {A[1][0], A[1][1] - lam, A[1][2]};
  const double r2[3] = {A[2][0], A[2][1], A[2][2] - lam};
  double c01[3], c02[3], c12[3];
  cross3(r0, r1, c01); cross3(r0, r2, c02); cross3(r1, r2, c12);
  const double n01 = dot3(c01, c01), n02 = dot3(c02, c02), n12 = dot3(c12, c12);
  const double* best = c01; double nb = n01;
  if (n02 > nb) { best = c02; nb = n02; }
  if (n12 > nb) { best = c12; nb = n12; }
  if (nb < 1e-280) { v[0] = 1.0; v[1] = 0.0; v[2] = 0.0; return; }
  const double inv = 1.0 / sqrt(nb);
  v[0] = best[0] * inv; v[1] = best[1] * inv; v[2] = best[2] * inv;
}

__global__ __launch_bounds__(256) void kabsch_svd(
    const float* __restrict__ mo, float* __restrict__ rmsd) {
  const int idx = blockIdx.x * blockDim.x + threadIdx.x;
  if (idx >= NPAIR) return;
  const float* m = mo + (size_t)idx * NMOM;
  const double invN = 1.0 / (double)N_;

  const double sP[3] = {m[0], m[1], m[2]};
  const double sQ[3] = {m[3], m[4], m[5]};
  double H[3][3];
#pragma unroll
  for (int i = 0; i < 3; ++i)
#pragma unroll
    for (int j = 0; j < 3; ++j)
      H[i][j] = (double)m[8 + 3 * i + j] - sP[i] * sQ[j] * invN;

  const double Sp = (double)m[6] - dot3(sP, sP) * invN;
  const double Sq = (double)m[7] - dot3(sQ, sQ) * invN;

  // A = H^T H (symmetric PSD)
  double A[3][3];
#pragma unroll
  for (int i = 0; i < 3; ++i)
#pragma unroll
    for (int j = 0; j < 3; ++j)
      A[i][j] = H[0][i] * H[0][j] + H[1][i] * H[1][j] + H[2][i] * H[2][j];

  double lam[3];
  double V[3][3];  // columns = eigenvectors
  const double q = (A[0][0] + A[1][1] + A[2][2]) / 3.0;
  const double p1 = A[0][1] * A[0][1] + A[0][2] * A[0][2] + A[1][2] * A[1][2];
  const double p2 = (A[0][0] - q) * (A[0][0] - q) +
                    (A[1][1] - q) * (A[1][1] - q) +
                    (A[2][2] - q) * (A[2][2] - q) + 2.0 * p1;
  if (p2 < 1e-30) {
    lam[0] = lam[1] = lam[2] = q;
#pragma unroll
    for (int i = 0; i < 3; ++i)
#pragma unroll
      for (int j = 0; j < 3; ++j) V[i][j] = (i == j) ? 1.0 : 0.0;
  } else {
    const double p = sqrt(p2 / 6.0);
    const double invp = 1.0 / p;
    double Bm[3][3];
#pragma unroll
    for (int i = 0; i < 3; ++i)
#pragma unroll
      for (int j = 0; j < 3; ++j)
        Bm[i][j] = (A[i][j] - ((i == j) ? q : 0.0)) * invp;
    const double detB =
        Bm[0][0] * (Bm[1][1] * Bm[2][2] - Bm[1][2] * Bm[2][1]) -
        Bm[0][1] * (Bm[1][0] * Bm[2][2] - Bm[1][2] * Bm[2][0]) +
        Bm[0][2] * (Bm[1][0] * Bm[2][1] - Bm[1][1] * Bm[2][0]);
    double r = detB * 0.5;
    r = fmin(1.0, fmax(-1.0, r));
    const double phi = acos(r) / 3.0;
    lam[0] = q + 2.0 * p * cos(phi);
    lam[2] = q + 2.0 * p * cos(phi + 2.0943951023931953);  // +2pi/3
    lam[1] = 3.0 * q - lam[0] - lam[2];

    double v1[3], v2[3], v3[3];
    eigvec3(A, lam[0], v1);
    eigvec3(A, lam[1], v2);
    // orthogonalize v2 against v1
    const double d12 = dot3(v1, v2);
    v2[0] -= d12 * v1[0]; v2[1] -= d12 * v1[1]; v2[2] -= d12 * v1[2];
    double n2 = dot3(v2, v2);
    if (n2 < 1e-24) {
      // fallback: orthogonalize a coordinate axis least aligned with v1
      const double a0 = fabs(v1[0]), a1f = fabs(v1[1]), a2f = fabs(v1[2]);
      int ax = (a0 <= a1f && a0 <= a2f) ? 0 : ((a1f <= a2f) ? 1 : 2);
      double e[3] = {0.0, 0.0, 0.0};
      e[ax] = 1.0;
      const double de = dot3(v1, e);
      v2[0] = e[0] - de * v1[0]; v2[1] = e[1] - de * v1[1]; v2[2] = e[2] - de * v1[2];
      n2 = dot3(v2, v2);
    }
    const double invn2 = 1.0 / sqrt(n2);
    v2[0] *= invn2; v2[1] *= invn2; v2[2] *= invn2;

    fixsign3(v1);
    fixsign3(v2);
    cross3(v1, v2, v3);
#pragma unroll
    for (int i = 0; i < 3; ++i) { V[i][0] = v1[i]; V[i][1] = v2[i]; V[i][2] = v3[i]; }
  }

  const double S0 = sqrt(fmax(lam[0], 0.0));
  const double S1 = sqrt(fmax(lam[1], 0.0));
  const double S2 = sqrt(fmax(lam[2], 0.0));

  const double detH =
      H[0][0] * (H[1][1] * H[2][2] - H[1][2] * H[2][1]) -
      H[0][1] * (H[1][0] * H[2][2] - H[1][2] * H[2][0]) +
      H[0][2] * (H[1][0] * H[2][1] - H[1][1] * H[2][0]);
  const double dsg = (detH >= 0.0) ? 1.0 : -1.0;

  // M = Vh*Vh (Vh = V^T): M_ii = sum_k V[k][i] * V[i][k]
  const double M00 = V[0][0] * V[0][0] + V[1][0] * V[0][1] + V[2][0] * V[0][2];
  const double M11 = V[0][1] * V[1][0] + V[1][1] * V[1][1] + V[2][1] * V[1][2];
  const double M22 = V[0][2] * V[2][0] + V[1][2] * V[2][1] + V[2][2] * V[2][2];

  const double T = S0 * M00 + S1 * M11 + dsg * S2 * M22;
  const double mse = (Sp + Sq - 2.0 * T) / (3.0 * (double)N_);
  rmsd[idx] = (float)sqrt(mse + 1e-8);
}

// ---------------------------------------------------------------------------
// Kernel 3: min over K, mean over B -> scalar
// ---------------------------------------------------------------------------
__global__ __launch_bounds__(256) void kabsch_final(
    const float* __restrict__ rmsd, float* __restrict__ out) {
  const int b = threadIdx.x;  // 256 threads == B_
  float mn = rmsd[b * K_];
#pragma unroll
  for (int k = 1; k < K_; ++k) mn = fminf(mn, rmsd[b * K_ + k]);
#pragma unroll
  for (int off = 32; off > 0; off >>= 1) mn += __shfl_down(mn, off, 64);
  __shared__ float s[4];
  if ((b & 63) == 0) s[b >> 6] = mn;
  __syncthreads();
  if (b == 0) out[0] = (s[0] + s[1] + s[2] + s[3]) * (1.0f / 256.0f);
}

extern "C" void kernel_launch(void* const* d_in, const int* in_sizes, int n_in,
                              void* d_out, int out_size, void* d_ws, size_t ws_size,
                              hipStream_t stream) {
  const float* preds = (const float*)d_in[0];
  const float* target = (const float*)d_in[1];
  float* out = (float*)d_out;
  float* mo = (float*)d_ws;                      // NPAIR*NMOM floats
  float* rm = mo + (size_t)NPAIR * NMOM;         // NPAIR floats

  hipLaunchKernelGGL(kabsch_moments, dim3(NPAIR), dim3(256), 0, stream,
                     preds, target, mo);
  hipLaunchKernelGGL(kabsch_svd, dim3((NPAIR + 255) / 256), dim3(256), 0, stream,
                     mo, rm);
  hipLaunchKernelGGL(kabsch_final, dim3(1), dim3(256), 0, stream, rm, out);
}

// Round 3
// 23.461 us; speedup vs baseline: 1.2847x; 1.2847x over previous
//
#include <hip/hip_runtime.h>
#include <math.h>

#define B_    256
#define K_    5
#define N_    4096
#define NPAIR (B_ * K_)     // 1280
#define NMOM  17

// ---------------------------------------------------------------------------
// Kernel 1: per-(b,k) moment reduction over N=4096 points.
// Block index remapped as idx = k*256 + b so that all K=5 blocks sharing the
// same target slice b land on the same XCD (256 % 8 == 0 -> idx%8 == b%8),
// making the 4 target re-reads per b L2-local (1.5 MB/XCD working set).
// Outputs 17 floats per pair: sumP[3], sumQ[3], sum|p|^2, sum|q|^2, H_raw[9]
// ---------------------------------------------------------------------------
__global__ __launch_bounds__(256) void kabsch_moments(
    const float* __restrict__ preds, const float* __restrict__ target,
    float* __restrict__ mout) {
  const int idx = blockIdx.x;         // 0..1279, idx = k*256 + b
  const int b = idx & 255;
  const int k = idx >> 8;
  const int pair_orig = b * K_ + k;   // preds memory order is [B,K,N,3]
  const int tid = threadIdx.x;

  const float4* __restrict__ P4 =
      reinterpret_cast<const float4*>(preds) + (size_t)pair_orig * (N_ * 3 / 4);
  const float4* __restrict__ Q4 =
      reinterpret_cast<const float4*>(target) + (size_t)b * (N_ * 3 / 4);

  float acc[NMOM];
#pragma unroll
  for (int i = 0; i < NMOM; ++i) acc[i] = 0.f;

  // 4096 points = 1024 chunks of 4 points (3 float4 each); 256 threads x 4 chunks
#pragma unroll
  for (int j = 0; j < 4; ++j) {
    const int c = tid + j * 256;
    const float4 a0 = P4[3 * c + 0], a1 = P4[3 * c + 1], a2 = P4[3 * c + 2];
    const float4 b0 = Q4[3 * c + 0], b1 = Q4[3 * c + 1], b2 = Q4[3 * c + 2];
    const float p[4][3] = {{a0.x, a0.y, a0.z},
                           {a0.w, a1.x, a1.y},
                           {a1.z, a1.w, a2.x},
                           {a2.y, a2.z, a2.w}};
    const float q[4][3] = {{b0.x, b0.y, b0.z},
                           {b0.w, b1.x, b1.y},
                           {b1.z, b1.w, b2.x},
                           {b2.y, b2.z, b2.w}};
#pragma unroll
    for (int m = 0; m < 4; ++m) {
      const float px = p[m][0], py = p[m][1], pz = p[m][2];
      const float qx = q[m][0], qy = q[m][1], qz = q[m][2];
      acc[0] += px; acc[1] += py; acc[2] += pz;
      acc[3] += qx; acc[4] += qy; acc[5] += qz;
      acc[6] = fmaf(px, px, fmaf(py, py, fmaf(pz, pz, acc[6])));
      acc[7] = fmaf(qx, qx, fmaf(qy, qy, fmaf(qz, qz, acc[7])));
      acc[8]  = fmaf(px, qx, acc[8]);
      acc[9]  = fmaf(px, qy, acc[9]);
      acc[10] = fmaf(px, qz, acc[10]);
      acc[11] = fmaf(py, qx, acc[11]);
      acc[12] = fmaf(py, qy, acc[12]);
      acc[13] = fmaf(py, qz, acc[13]);
      acc[14] = fmaf(pz, qx, acc[14]);
      acc[15] = fmaf(pz, qy, acc[15]);
      acc[16] = fmaf(pz, qz, acc[16]);
    }
  }

  // wave64 butterfly reduce, then cross-wave via LDS
#pragma unroll
  for (int off = 32; off > 0; off >>= 1) {
#pragma unroll
    for (int i = 0; i < NMOM; ++i) acc[i] += __shfl_down(acc[i], off, 64);
  }

  __shared__ float red[4][NMOM];
  const int lane = tid & 63, wid = tid >> 6;
  if (lane == 0) {
#pragma unroll
    for (int i = 0; i < NMOM; ++i) red[wid][i] = acc[i];
  }
  __syncthreads();
  if (tid < NMOM) {
    mout[(size_t)idx * NMOM + tid] =
        red[0][tid] + red[1][tid] + red[2][tid] + red[3][tid];
  }
}

// ---------------------------------------------------------------------------
// Kernel 2: per-pair 3x3 "SVD" (eigendecomposition of H^T H) + rmsd.
// Reproduces the reference's buggy R = Vh diag(1,1,d) U^T via
//   tr(H R) = S0*M00 + S1*M11 + d*S2*M22,  M = Vh*Vh, d = sign(det H).
// ---------------------------------------------------------------------------
__device__ inline void cross3(const double* a, const double* b, double* c) {
  c[0] = a[1] * b[2] - a[2] * b[1];
  c[1] = a[2] * b[0] - a[0] * b[2];
  c[2] = a[0] * b[1] - a[1] * b[0];
}
__device__ inline double dot3(const double* a, const double* b) {
  return a[0] * b[0] + a[1] * b[1] + a[2] * b[2];
}
__device__ inline void fixsign3(double* v) {
  const double a0 = fabs(v[0]), a1 = fabs(v[1]), a2 = fabs(v[2]);
  const int i = (a0 >= a1 && a0 >= a2) ? 0 : ((a1 >= a2) ? 1 : 2);
  if (v[i] < 0.0) { v[0] = -v[0]; v[1] = -v[1]; v[2] = -v[2]; }
}
__device__ inline void eigvec3(const double A[3][3], double lam, double* v) {
  const double r0[3] = {A[0][0] - lam, A[0][1], A[0][2]};
  const double r1[3] = {A[1][0], A[1][1] - lam, A[1][2]};
  const double r2[3] = {A[2][0], A[2][1], A[2][2] - lam};
  double c01[3], c02[3], c12[3];
  cross3(r0, r1, c01); cross3(r0, r2, c02); cross3(r1, r2, c12);
  const double n01 = dot3(c01, c01), n02 = dot3(c02, c02), n12 = dot3(c12, c12);
  const double* best = c01; double nb = n01;
  if (n02 > nb) { best = c02; nb = n02; }
  if (n12 > nb) { best = c12; nb = n12; }
  if (nb < 1e-280) { v[0] = 1.0; v[1] = 0.0; v[2] = 0.0; return; }
  const double inv = 1.0 / sqrt(nb);
  v[0] = best[0] * inv; v[1] = best[1] * inv; v[2] = best[2] * inv;
}

__global__ __launch_bounds__(256) void kabsch_svd(
    const float* __restrict__ mo, float* __restrict__ rmsd) {
  const int idx = blockIdx.x * blockDim.x + threadIdx.x;
  if (idx >= NPAIR) return;
  const float* m = mo + (size_t)idx * NMOM;
  const double invN = 1.0 / (double)N_;

  const double sP[3] = {m[0], m[1], m[2]};
  const double sQ[3] = {m[3], m[4], m[5]};
  double H[3][3];
#pragma unroll
  for (int i = 0; i < 3; ++i)
#pragma unroll
    for (int j = 0; j < 3; ++j)
      H[i][j] = (double)m[8 + 3 * i + j] - sP[i] * sQ[j] * invN;

  const double Sp = (double)m[6] - dot3(sP, sP) * invN;
  const double Sq = (double)m[7] - dot3(sQ, sQ) * invN;

  // A = H^T H (symmetric PSD)
  double A[3][3];
#pragma unroll
  for (int i = 0; i < 3; ++i)
#pragma unroll
    for (int j = 0; j < 3; ++j)
      A[i][j] = H[0][i] * H[0][j] + H[1][i] * H[1][j] + H[2][i] * H[2][j];

  double lam[3];
  double V[3][3];  // columns = eigenvectors
  const double q = (A[0][0] + A[1][1] + A[2][2]) / 3.0;
  const double p1 = A[0][1] * A[0][1] + A[0][2] * A[0][2] + A[1][2] * A[1][2];
  const double p2 = (A[0][0] - q) * (A[0][0] - q) +
                    (A[1][1] - q) * (A[1][1] - q) +
                    (A[2][2] - q) * (A[2][2] - q) + 2.0 * p1;
  if (p2 < 1e-30) {
    lam[0] = lam[1] = lam[2] = q;
#pragma unroll
    for (int i = 0; i < 3; ++i)
#pragma unroll
      for (int j = 0; j < 3; ++j) V[i][j] = (i == j) ? 1.0 : 0.0;
  } else {
    const double p = sqrt(p2 / 6.0);
    const double invp = 1.0 / p;
    double Bm[3][3];
#pragma unroll
    for (int i = 0; i < 3; ++i)
#pragma unroll
      for (int j = 0; j < 3; ++j)
        Bm[i][j] = (A[i][j] - ((i == j) ? q : 0.0)) * invp;
    const double detB =
        Bm[0][0] * (Bm[1][1] * Bm[2][2] - Bm[1][2] * Bm[2][1]) -
        Bm[0][1] * (Bm[1][0] * Bm[2][2] - Bm[1][2] * Bm[2][0]) +
        Bm[0][2] * (Bm[1][0] * Bm[2][1] - Bm[1][1] * Bm[2][0]);
    double r = detB * 0.5;
    r = fmin(1.0, fmax(-1.0, r));
    const double phi = acos(r) / 3.0;
    lam[0] = q + 2.0 * p * cos(phi);
    lam[2] = q + 2.0 * p * cos(phi + 2.0943951023931953);  // +2pi/3
    lam[1] = 3.0 * q - lam[0] - lam[2];

    double v1[3], v2[3], v3[3];
    eigvec3(A, lam[0], v1);
    eigvec3(A, lam[1], v2);
    // orthogonalize v2 against v1
    const double d12 = dot3(v1, v2);
    v2[0] -= d12 * v1[0]; v2[1] -= d12 * v1[1]; v2[2] -= d12 * v1[2];
    double n2 = dot3(v2, v2);
    if (n2 < 1e-24) {
      // fallback: orthogonalize a coordinate axis least aligned with v1
      const double a0 = fabs(v1[0]), a1f = fabs(v1[1]), a2f = fabs(v1[2]);
      int ax = (a0 <= a1f && a0 <= a2f) ? 0 : ((a1f <= a2f) ? 1 : 2);
      double e[3] = {0.0, 0.0, 0.0};
      e[ax] = 1.0;
      const double de = dot3(v1, e);
      v2[0] = e[0] - de * v1[0]; v2[1] = e[1] - de * v1[1]; v2[2] = e[2] - de * v1[2];
      n2 = dot3(v2, v2);
    }
    const double invn2 = 1.0 / sqrt(n2);
    v2[0] *= invn2; v2[1] *= invn2; v2[2] *= invn2;

    fixsign3(v1);
    fixsign3(v2);
    cross3(v1, v2, v3);
#pragma unroll
    for (int i = 0; i < 3; ++i) { V[i][0] = v1[i]; V[i][1] = v2[i]; V[i][2] = v3[i]; }
  }

  const double S0 = sqrt(fmax(lam[0], 0.0));
  const double S1 = sqrt(fmax(lam[1], 0.0));
  const double S2 = sqrt(fmax(lam[2], 0.0));

  const double detH =
      H[0][0] * (H[1][1] * H[2][2] - H[1][2] * H[2][1]) -
      H[0][1] * (H[1][0] * H[2][2] - H[1][2] * H[2][0]) +
      H[0][2] * (H[1][0] * H[2][1] - H[1][1] * H[2][0]);
  const double dsg = (detH >= 0.0) ? 1.0 : -1.0;

  // M = Vh*Vh (Vh = V^T): M_ii = sum_k V[k][i] * V[i][k]
  const double M00 = V[0][0] * V[0][0] + V[1][0] * V[0][1] + V[2][0] * V[0][2];
  const double M11 = V[0][1] * V[1][0] + V[1][1] * V[1][1] + V[2][1] * V[1][2];
  const double M22 = V[0][2] * V[2][0] + V[1][2] * V[2][1] + V[2][2] * V[2][2];

  const double T = S0 * M00 + S1 * M11 + dsg * S2 * M22;
  const double mse = (Sp + Sq - 2.0 * T) / (3.0 * (double)N_);
  rmsd[idx] = (float)sqrt(mse + 1e-8);
}

// ---------------------------------------------------------------------------
// Kernel 3: min over K, mean over B -> scalar.
// rmsd layout is idx = k*256 + b, so per-b min reads stride-256 (coalesced).
// ---------------------------------------------------------------------------
__global__ __launch_bounds__(256) void kabsch_final(
    const float* __restrict__ rmsd, float* __restrict__ out) {
  const int b = threadIdx.x;  // 256 threads == B_
  float mn = rmsd[b];
#pragma unroll
  for (int k = 1; k < K_; ++k) mn = fminf(mn, rmsd[k * 256 + b]);
#pragma unroll
  for (int off = 32; off > 0; off >>= 1) mn += __shfl_down(mn, off, 64);
  __shared__ float s[4];
  if ((b & 63) == 0) s[b >> 6] = mn;
  __syncthreads();
  if (b == 0) out[0] = (s[0] + s[1] + s[2] + s[3]) * (1.0f / 256.0f);
}

extern "C" void kernel_launch(void* const* d_in, const int* in_sizes, int n_in,
                              void* d_out, int out_size, void* d_ws, size_t ws_size,
                              hipStream_t stream) {
  const float* preds = (const float*)d_in[0];
  const float* target = (const float*)d_in[1];
  float* out = (float*)d_out;
  float* mo = (float*)d_ws;                      // NPAIR*NMOM floats
  float* rm = mo + (size_t)NPAIR * NMOM;         // NPAIR floats

  hipLaunchKernelGGL(kabsch_moments, dim3(NPAIR), dim3(256), 0, stream,
                     preds, target, mo);
  hipLaunchKernelGGL(kabsch_svd, dim3((NPAIR + 255) / 256), dim3(256), 0, stream,
                     mo, rm);
  hipLaunchKernelGGL(kabsch_final, dim3(1), dim3(256), 0, stream, rm, out);
}